// Round 12
// baseline (15131.992 us; speedup 1.0000x reference)
//
#include <hip/hip_runtime.h>

// Residual VQ — np-f32 bit-faithful. Round 12: codebook reads go DIRECT from
// global/L2 (no c_s LDS staging). Rationale: c has zero cross-wave reuse
// (each k owned by one wave; tg-broadcast is intra-instruction), so LDS
// staging paid ds_write + ds_read + 2 barriers/slice for nothing. This
// halves LDS-pipe instructions (the measured bottleneck: 3072 vs 2048 FMA
// cyc/slice/CU), removes all per-slice barriers (520 -> 32 per block), and
// lets waves drift to overlap VMEM/LDS/FMA. Numerics bit-identical: cv bytes
// are the same, every acc chain keeps exact d-ascending fmaf order.
//
// Frozen numerics (validated rounds 4/6/8/9/10/11):
//   dot:   single sequential fmaf chain over d=0..255 ascending per (tok,k)
//   A,C:   np pairwise-sum-of-squares (AVX512 tree) replica
//   dist:  fl(fl(A - fl(2*dot)) + C), argmin strict-<, first-index ties
//   resid: r = fl(r - c[idx]) elementwise
//
// Org: block = 32 tokens, 512 threads = 8 waves. Wave w owns k in
// [128w, 128w+128). Lane grid 4 tg x 16 kg; per lane 8 tokens (tg+4i) x
// 8 k (128w+kg+16j), acc[8][8] persists over 32 d-slices of 8.
// LDS (~35 KB): r_m[32][260] row-major only.

#define NTOK 131072
#define DEPTH 8
#define KCB 1024
#define DIM 256
#define TM 32
#define DS 8
#define NSLICE (DIM / DS)
#define RP 260

__device__ __forceinline__ float np_sumsq_128(const float* p) {
  float s[16];
#pragma unroll
  for (int l = 0; l < 16; ++l) {
    float r0 = __fadd_rn(__fmul_rn(p[l], p[l]),
                         __fmul_rn(p[l + 64], p[l + 64]));
    float r1 = __fadd_rn(__fmul_rn(p[l + 16], p[l + 16]),
                         __fmul_rn(p[l + 80], p[l + 80]));
    float r2 = __fadd_rn(__fmul_rn(p[l + 32], p[l + 32]),
                         __fmul_rn(p[l + 96], p[l + 96]));
    float r3 = __fadd_rn(__fmul_rn(p[l + 48], p[l + 48]),
                         __fmul_rn(p[l + 112], p[l + 112]));
    s[l] = __fadd_rn(__fadd_rn(r0, r1), __fadd_rn(r2, r3));
  }
  float t[8];
#pragma unroll
  for (int l = 0; l < 8; ++l) t[l] = __fadd_rn(s[l], s[l + 8]);
  float u[4];
#pragma unroll
  for (int l = 0; l < 4; ++l) u[l] = __fadd_rn(t[l], t[l + 4]);
  return __fadd_rn(__fadd_rn(u[0], u[2]), __fadd_rn(u[1], u[3]));
}

__device__ __forceinline__ float np_sumsq_256(const float* p) {
  return __fadd_rn(np_sumsq_128(p), np_sumsq_128(p + 128));
}

__global__ __launch_bounds__(256) void c2_kernel(const float* __restrict__ cbs,
                                                 float* __restrict__ C32g) {
  int gid = blockIdx.x * 256 + threadIdx.x;
  C32g[gid] = np_sumsq_256(cbs + (size_t)gid * DIM);
}

__global__ __launch_bounds__(512, 1) void rvq_kernel(
    const float* __restrict__ latent, const float* __restrict__ cbs,
    const float* __restrict__ C32g, float* __restrict__ out) {
  __shared__ float r_m[TM][RP];
  __shared__ float A_s[TM];
  __shared__ float best_s[8][TM];
  __shared__ int bidx_s[8][TM];
  __shared__ int idx_s[TM];

  const int tid = threadIdx.x;
  const int w = tid >> 6;
  const int lane = tid & 63;
  const int tg = lane >> 4;
  const int kg = lane & 15;
  const int n0 = blockIdx.x * TM;

  // ---- stage latent -> r_m (exact copy) ----
  {
    int tok = tid >> 4;
    int db = (tid & 15) * 16;
    const float* src = latent + (size_t)(n0 + tok) * DIM + db;
#pragma unroll
    for (int j = 0; j < 4; ++j)
      *(float4*)&r_m[tok][db + j * 4] = *(const float4*)(src + j * 4);
  }
  __syncthreads();

  const int kbase = w * 128 + kg;  // lane's k_j = kbase + 16*j

  for (int lvl = 0; lvl < DEPTH; ++lvl) {
    const float* cb = cbs + (size_t)lvl * KCB * DIM;
    if (tid < TM) A_s[tid] = np_sumsq_256(&r_m[tid][0]);

    // lane's codebook base: rows kbase+16j are at cbl + j*16384 floats? no:
    // (16 rows)*(256 f) = 4096 floats per j step.
    const float* cbl = cb + (size_t)kbase * DIM;

    float acc[8][8];
#pragma unroll
    for (int i = 0; i < 8; ++i)
#pragma unroll
      for (int j = 0; j < 8; ++j) acc[i][j] = 0.f;

    for (int ds = 0; ds < NSLICE; ++ds) {
#pragma unroll
      for (int sub = 0; sub < 2; ++sub) {
        const int d0 = ds * DS + sub * 4;
        // global cv loads (L2-resident; vmcnt-hidden under FMA burst)
        float4 cv[8];
#pragma unroll
        for (int j = 0; j < 8; ++j)
          cv[j] = *(const float4*)(cbl + j * (16 * DIM) + d0);
        // LDS rv loads (conflict-free: 4 rows on distinct bank quads,
        // 16-lane broadcast within each)
        float4 rv[8];
#pragma unroll
        for (int i = 0; i < 8; ++i)
          rv[i] = *(const float4*)&r_m[tg + 4 * i][d0];
        // 256 FMAs; each acc chain strictly d-ascending
#pragma unroll
        for (int j = 0; j < 8; ++j)
#pragma unroll
          for (int i = 0; i < 8; ++i) {
            float a = acc[i][j];
            a = fmaf(rv[i].x, cv[j].x, a);
            a = fmaf(rv[i].y, cv[j].y, a);
            a = fmaf(rv[i].z, cv[j].z, a);
            a = fmaf(rv[i].w, cv[j].w, a);
            acc[i][j] = a;
          }
      }
    }

    __syncthreads();  // A_s written (wave 0 passed here => A_s done)

    // ---- dist combine + per-lane argmin (j ascending = k ascending) ----
    float bv[8];
    int bk[8];
#pragma unroll
    for (int i = 0; i < 8; ++i) {
      bv[i] = 3.4e38f;
      bk[i] = 0;
    }
#pragma unroll
    for (int j = 0; j < 8; ++j) {
      const int k = kbase + 16 * j;
      const float C = C32g[lvl * KCB + k];
#pragma unroll
      for (int i = 0; i < 8; ++i) {
        float d = __fadd_rn(
            __fsub_rn(A_s[tg + 4 * i], __fmul_rn(2.0f, acc[i][j])), C);
        if (d < bv[i]) {
          bv[i] = d;
          bk[i] = k;
        }
      }
    }

    // ---- butterfly over the 16 kg lanes (index tie-break) ----
#pragma unroll
    for (int m = 1; m <= 8; m <<= 1) {
#pragma unroll
      for (int i = 0; i < 8; ++i) {
        float ov = __shfl_xor(bv[i], m);
        int ok = __shfl_xor(bk[i], m);
        if (ov < bv[i] || (ov == bv[i] && ok < bk[i])) {
          bv[i] = ov;
          bk[i] = ok;
        }
      }
    }
    if (kg == 0) {
#pragma unroll
      for (int i = 0; i < 8; ++i) {
        best_s[w][tg + 4 * i] = bv[i];
        bidx_s[w][tg + 4 * i] = bk[i];
      }
    }
    __syncthreads();

    // ---- cross-wave merge (w ascending = k ascending; strict <) ----
    if (tid < TM) {
      float b = best_s[0][tid];
      int k = bidx_s[0][tid];
#pragma unroll
      for (int ww = 1; ww < 8; ++ww) {
        float ov = best_s[ww][tid];
        int ok = bidx_s[ww][tid];
        if (ov < b || (ov == b && ok < k)) {
          b = ov;
          k = ok;
        }
      }
      idx_s[tid] = k;
      out[(size_t)NTOK * DIM + (size_t)lvl * NTOK + n0 + tid] = (float)k;
    }
    __syncthreads();

    // ---- residual update: r = fl(r - c[idx]) elementwise ----
    {
      int tok = tid >> 4;
      int db = (tid & 15) * 16;
      const float* crow = cb + (size_t)idx_s[tok] * DIM + db;
#pragma unroll
      for (int j = 0; j < 4; ++j) {
        float4 cv4 = *(const float4*)(crow + j * 4);
        int d = db + j * 4;
        r_m[tok][d + 0] = __fsub_rn(r_m[tok][d + 0], cv4.x);
        r_m[tok][d + 1] = __fsub_rn(r_m[tok][d + 1], cv4.y);
        r_m[tok][d + 2] = __fsub_rn(r_m[tok][d + 2], cv4.z);
        r_m[tok][d + 3] = __fsub_rn(r_m[tok][d + 3], cv4.w);
      }
    }
    __syncthreads();  // r stable before next level's A_s + d-loop
  }

  // ---- straight_through = fl(l + fl(q - l)), q = fl(l - r) ----
  {
    int tok = tid >> 4;
    int db = (tid & 15) * 16;
#pragma unroll
    for (int j = 0; j < 4; ++j) {
      int d = db + j * 4;
      size_t gi = (size_t)(n0 + tok) * DIM + d;
      float4 l4 = *(const float4*)(latent + gi);
      float4 qv;
      float q;
      q = __fsub_rn(l4.x, r_m[tok][d + 0]);
      qv.x = __fadd_rn(l4.x, __fsub_rn(q, l4.x));
      q = __fsub_rn(l4.y, r_m[tok][d + 1]);
      qv.y = __fadd_rn(l4.y, __fsub_rn(q, l4.y));
      q = __fsub_rn(l4.z, r_m[tok][d + 2]);
      qv.z = __fadd_rn(l4.z, __fsub_rn(q, l4.z));
      q = __fsub_rn(l4.w, r_m[tok][d + 3]);
      qv.w = __fadd_rn(l4.w, __fsub_rn(q, l4.w));
      *(float4*)(out + gi) = qv;
    }
  }
}

extern "C" void kernel_launch(void* const* d_in, const int* in_sizes, int n_in,
                              void* d_out, int out_size, void* d_ws,
                              size_t ws_size, hipStream_t stream) {
  const float* latent = (const float*)d_in[0];
  const float* codebooks = (const float*)d_in[1];
  float* out = (float*)d_out;
  float* C32g = (float*)d_ws;  // 8192 floats

  hipLaunchKernelGGL(c2_kernel, dim3(DEPTH * KCB / 256), dim3(256), 0, stream,
                     codebooks, C32g);
  hipLaunchKernelGGL(rvq_kernel, dim3(NTOK / TM), dim3(512), 0, stream, latent,
                     codebooks, C32g, out);
}

// Round 13
// 7183.062 us; speedup vs baseline: 2.1066x; 2.1066x over previous
//
#include <hip/hip_runtime.h>

// Residual VQ — np-f32 bit-faithful. Round 13: COALESCED direct-global c.
// r12 failed because k-major codebook rows gave 1KB-strided lane addresses
// (64 cache-line requests per instr). Fix: precompute d-major transpose
// ct[lvl][d4][k][4] in d_ws; for fixed (d4,j) the 16 kg-lanes read 16
// consecutive float4s = one 256B segment (tg-broadcast x4). No c LDS staging,
// no per-slice barriers (~4/level). LDS carries only r (768 cyc/CU/sub <
// FMA 1024). Numerics bit-identical (same bytes, same d-ascending chains).
//
// Frozen numerics (validated rounds 4/6/8-12):
//   dot:   single sequential fmaf chain over d=0..255 ascending per (tok,k)
//   A,C:   np pairwise-sum-of-squares (AVX512 tree) replica
//   dist:  fl(fl(A - fl(2*dot)) + C), argmin strict-<, first-index ties
//   resid: r = fl(r - c[idx]) elementwise
//
// Org: block = 32 tokens, 512 threads = 8 waves. Wave w owns k in
// [128w,128w+128). Lane 4tg x 16kg; per lane 8 tok x 8 k, acc[8][8] over
// 64 d-steps of 4. LDS ~35 KB: r_m[32][260] only.

#define NTOK 131072
#define DEPTH 8
#define KCB 1024
#define DIM 256
#define TM 32
#define RP 260

__device__ __forceinline__ float np_sumsq_128(const float* p) {
  float s[16];
#pragma unroll
  for (int l = 0; l < 16; ++l) {
    float r0 = __fadd_rn(__fmul_rn(p[l], p[l]),
                         __fmul_rn(p[l + 64], p[l + 64]));
    float r1 = __fadd_rn(__fmul_rn(p[l + 16], p[l + 16]),
                         __fmul_rn(p[l + 80], p[l + 80]));
    float r2 = __fadd_rn(__fmul_rn(p[l + 32], p[l + 32]),
                         __fmul_rn(p[l + 96], p[l + 96]));
    float r3 = __fadd_rn(__fmul_rn(p[l + 48], p[l + 48]),
                         __fmul_rn(p[l + 112], p[l + 112]));
    s[l] = __fadd_rn(__fadd_rn(r0, r1), __fadd_rn(r2, r3));
  }
  float t[8];
#pragma unroll
  for (int l = 0; l < 8; ++l) t[l] = __fadd_rn(s[l], s[l + 8]);
  float u[4];
#pragma unroll
  for (int l = 0; l < 4; ++l) u[l] = __fadd_rn(t[l], t[l + 4]);
  return __fadd_rn(__fadd_rn(u[0], u[2]), __fadd_rn(u[1], u[3]));
}

__device__ __forceinline__ float np_sumsq_256(const float* p) {
  return __fadd_rn(np_sumsq_128(p), np_sumsq_128(p + 128));
}

__global__ __launch_bounds__(256) void c2_kernel(const float* __restrict__ cbs,
                                                 float* __restrict__ C32g) {
  int gid = blockIdx.x * 256 + threadIdx.x;
  C32g[gid] = np_sumsq_256(cbs + (size_t)gid * DIM);
}

// ct[((lvl*64 + d4)*1024 + k)*4 + e] = cbs[lvl][k][d4*4+e]
__global__ __launch_bounds__(256) void transpose_kernel(
    const float* __restrict__ cbs, float* __restrict__ ct) {
  int gid = blockIdx.x * 256 + threadIdx.x;  // 8*64*1024 threads
  int k = gid & 1023;
  int ld4 = gid >> 10;
  int lvl = ld4 >> 6, d4 = ld4 & 63;
  const float* src = cbs + ((size_t)lvl * KCB + k) * DIM + d4 * 4;
  float4 v = *(const float4*)src;
  *(float4*)&ct[(size_t)gid * 4] = v;
}

__global__ __launch_bounds__(512, 1) void rvq_kernel(
    const float* __restrict__ latent, const float* __restrict__ cbs,
    const float* __restrict__ C32g, const float* __restrict__ ct,
    float* __restrict__ out) {
  __shared__ float r_m[TM][RP];
  __shared__ float A_s[TM];
  __shared__ float best_s[8][TM];
  __shared__ int bidx_s[8][TM];
  __shared__ int idx_s[TM];

  const int tid = threadIdx.x;
  const int w = tid >> 6;
  const int lane = tid & 63;
  const int tg = lane >> 4;
  const int kg = lane & 15;
  const int n0 = blockIdx.x * TM;
  const bool use_ct = (ct != nullptr);

  // ---- stage latent -> r_m (exact copy) ----
  {
    int tok = tid >> 4;
    int db = (tid & 15) * 16;
    const float* src = latent + (size_t)(n0 + tok) * DIM + db;
#pragma unroll
    for (int j = 0; j < 4; ++j)
      *(float4*)&r_m[tok][db + j * 4] = *(const float4*)(src + j * 4);
  }
  __syncthreads();

  const int kbase = w * 128 + kg;  // lane's k_j = kbase + 16*j

  for (int lvl = 0; lvl < DEPTH; ++lvl) {
    const float* cb = cbs + (size_t)lvl * KCB * DIM;
    if (tid < TM) A_s[tid] = np_sumsq_256(&r_m[tid][0]);

    float acc[8][8];
#pragma unroll
    for (int i = 0; i < 8; ++i)
#pragma unroll
      for (int j = 0; j < 8; ++j) acc[i][j] = 0.f;

    if (use_ct) {
      // lane base into transposed codebook for this level
      const float* ctl = ct + ((size_t)lvl * 64 * KCB + kbase) * 4;
#pragma unroll 2
      for (int d4 = 0; d4 < 64; ++d4) {
        const int d0 = d4 * 4;
        const float* p = ctl + (size_t)d4 * KCB * 4;
        float4 cv[8];
#pragma unroll
        for (int j = 0; j < 8; ++j)
          cv[j] = *(const float4*)(p + j * 64);  // 16 k-stride = 64 floats
        float4 rv[8];
#pragma unroll
        for (int i = 0; i < 8; ++i)
          rv[i] = *(const float4*)&r_m[tg + 4 * i][d0];
#pragma unroll
        for (int j = 0; j < 8; ++j)
#pragma unroll
          for (int i = 0; i < 8; ++i) {
            float a = acc[i][j];
            a = fmaf(rv[i].x, cv[j].x, a);
            a = fmaf(rv[i].y, cv[j].y, a);
            a = fmaf(rv[i].z, cv[j].z, a);
            a = fmaf(rv[i].w, cv[j].w, a);
            acc[i][j] = a;
          }
      }
    } else {
      // fallback (ws too small): r12-style strided loads — correct, slower
      const float* cbl = cb + (size_t)kbase * DIM;
#pragma unroll 2
      for (int d4 = 0; d4 < 64; ++d4) {
        const int d0 = d4 * 4;
        float4 cv[8];
#pragma unroll
        for (int j = 0; j < 8; ++j)
          cv[j] = *(const float4*)(cbl + j * (16 * DIM) + d0);
        float4 rv[8];
#pragma unroll
        for (int i = 0; i < 8; ++i)
          rv[i] = *(const float4*)&r_m[tg + 4 * i][d0];
#pragma unroll
        for (int j = 0; j < 8; ++j)
#pragma unroll
          for (int i = 0; i < 8; ++i) {
            float a = acc[i][j];
            a = fmaf(rv[i].x, cv[j].x, a);
            a = fmaf(rv[i].y, cv[j].y, a);
            a = fmaf(rv[i].z, cv[j].z, a);
            a = fmaf(rv[i].w, cv[j].w, a);
            acc[i][j] = a;
          }
      }
    }

    __syncthreads();  // A_s complete before combine

    // ---- dist combine + per-lane argmin (j ascending = k ascending) ----
    float bv[8];
    int bk[8];
#pragma unroll
    for (int i = 0; i < 8; ++i) {
      bv[i] = 3.4e38f;
      bk[i] = 0;
    }
#pragma unroll
    for (int j = 0; j < 8; ++j) {
      const int k = kbase + 16 * j;
      const float C = C32g[lvl * KCB + k];
#pragma unroll
      for (int i = 0; i < 8; ++i) {
        float d = __fadd_rn(
            __fsub_rn(A_s[tg + 4 * i], __fmul_rn(2.0f, acc[i][j])), C);
        if (d < bv[i]) {
          bv[i] = d;
          bk[i] = k;
        }
      }
    }

    // ---- butterfly over the 16 kg lanes (index tie-break) ----
#pragma unroll
    for (int m = 1; m <= 8; m <<= 1) {
#pragma unroll
      for (int i = 0; i < 8; ++i) {
        float ov = __shfl_xor(bv[i], m);
        int ok = __shfl_xor(bk[i], m);
        if (ov < bv[i] || (ov == bv[i] && ok < bk[i])) {
          bv[i] = ov;
          bk[i] = ok;
        }
      }
    }
    if (kg == 0) {
#pragma unroll
      for (int i = 0; i < 8; ++i) {
        best_s[w][tg + 4 * i] = bv[i];
        bidx_s[w][tg + 4 * i] = bk[i];
      }
    }
    __syncthreads();

    // ---- cross-wave merge (w ascending = k ascending; strict <) ----
    if (tid < TM) {
      float b = best_s[0][tid];
      int k = bidx_s[0][tid];
#pragma unroll
      for (int ww = 1; ww < 8; ++ww) {
        float ov = best_s[ww][tid];
        int ok = bidx_s[ww][tid];
        if (ov < b || (ov == b && ok < k)) {
          b = ov;
          k = ok;
        }
      }
      idx_s[tid] = k;
      out[(size_t)NTOK * DIM + (size_t)lvl * NTOK + n0 + tid] = (float)k;
    }
    __syncthreads();

    // ---- residual update: r = fl(r - c[idx]) elementwise ----
    {
      int tok = tid >> 4;
      int db = (tid & 15) * 16;
      const float* crow = cb + (size_t)idx_s[tok] * DIM + db;
#pragma unroll
      for (int j = 0; j < 4; ++j) {
        float4 cv4 = *(const float4*)(crow + j * 4);
        int d = db + j * 4;
        r_m[tok][d + 0] = __fsub_rn(r_m[tok][d + 0], cv4.x);
        r_m[tok][d + 1] = __fsub_rn(r_m[tok][d + 1], cv4.y);
        r_m[tok][d + 2] = __fsub_rn(r_m[tok][d + 2], cv4.z);
        r_m[tok][d + 3] = __fsub_rn(r_m[tok][d + 3], cv4.w);
      }
    }
    __syncthreads();  // r stable before next level's A_s + d-loop
  }

  // ---- straight_through = fl(l + fl(q - l)), q = fl(l - r) ----
  {
    int tok = tid >> 4;
    int db = (tid & 15) * 16;
#pragma unroll
    for (int j = 0; j < 4; ++j) {
      int d = db + j * 4;
      size_t gi = (size_t)(n0 + tok) * DIM + d;
      float4 l4 = *(const float4*)(latent + gi);
      float4 qv;
      float q;
      q = __fsub_rn(l4.x, r_m[tok][d + 0]);
      qv.x = __fadd_rn(l4.x, __fsub_rn(q, l4.x));
      q = __fsub_rn(l4.y, r_m[tok][d + 1]);
      qv.y = __fadd_rn(l4.y, __fsub_rn(q, l4.y));
      q = __fsub_rn(l4.z, r_m[tok][d + 2]);
      qv.z = __fadd_rn(l4.z, __fsub_rn(q, l4.z));
      q = __fsub_rn(l4.w, r_m[tok][d + 3]);
      qv.w = __fadd_rn(l4.w, __fsub_rn(q, l4.w));
      *(float4*)(out + gi) = qv;
    }
  }
}

extern "C" void kernel_launch(void* const* d_in, const int* in_sizes, int n_in,
                              void* d_out, int out_size, void* d_ws,
                              size_t ws_size, hipStream_t stream) {
  const float* latent = (const float*)d_in[0];
  const float* codebooks = (const float*)d_in[1];
  float* out = (float*)d_out;
  float* C32g = (float*)d_ws;  // 8192 floats = 32 KB

  const size_t ct_floats = (size_t)DEPTH * 64 * KCB * 4;  // 8.4 MB
  float* ct = nullptr;
  if (ws_size >= 8192 * sizeof(float) + ct_floats * sizeof(float)) {
    ct = (float*)d_ws + 8192;
    hipLaunchKernelGGL(transpose_kernel, dim3(DEPTH * 64 * KCB / 256),
                       dim3(256), 0, stream, codebooks, ct);
  }
  hipLaunchKernelGGL(c2_kernel, dim3(DEPTH * KCB / 256), dim3(256), 0, stream,
                     codebooks, C32g);
  hipLaunchKernelGGL(rvq_kernel, dim3(NTOK / TM), dim3(512), 0, stream, latent,
                     codebooks, C32g, ct, out);
}